// Round 1
// baseline (2288.860 us; speedup 1.0000x reference)
//
#include <hip/hip_runtime.h>
#include <hip/hip_bf16.h>
#include <cstdint>
#include <cstddef>

#define E_N 32
#define H_N 2048
#define I_N 1536
#define T_N 1024
#define K_N 8
#define GU_N (2 * I_N)   // 3072

// GEMM tiling
#define BM 128
#define BN 128
#define BK 32
#define LSTR 40          // 32 + 8 pad (bf16 elems): 2-way-only bank aliasing, 16B-aligned rows

typedef __attribute__((ext_vector_type(8))) short short8;
typedef __attribute__((ext_vector_type(4))) short short4v;
typedef __attribute__((ext_vector_type(4))) float float4v;

__device__ __forceinline__ ushort f2bf(float f) {
  union { float f; uint32_t u; } v; v.f = f;
  uint32_t u = v.u;
  return (ushort)((u + 0x7fffu + ((u >> 16) & 1u)) >> 16);  // RNE
}
__device__ __forceinline__ float bf2f(ushort h) {
  union { uint32_t u; float f; } v; v.u = ((uint32_t)h) << 16;
  return v.f;
}

// ---------------- bookkeeping kernels ----------------

__global__ void k_init(float* w_full, int* cnt) {
  int i = blockIdx.x * 256 + threadIdx.x;
  if (i < T_N * E_N) w_full[i] = 0.f;
  if (i < E_N) cnt[i] = 0;
}

__global__ void k_scatter(const int* __restrict__ idx, const float* __restrict__ w,
                          float* __restrict__ w_full) {
  int i = blockIdx.x * 256 + threadIdx.x;  // over T*K
  if (i >= T_N * K_N) return;
  int t = i / K_N;
  int e = idx[i];
  atomicAdd(&w_full[t * E_N + e], w[i]);
}

__global__ void k_build(const float* __restrict__ w_full, int* __restrict__ cnt,
                        int* __restrict__ tok, float* __restrict__ wgt) {
  int i = blockIdx.x * 256 + threadIdx.x;  // over T*E
  if (i >= T_N * E_N) return;
  int t = i / E_N, e = i % E_N;
  float v = w_full[i];
  if (v != 0.f) {
    int p = atomicAdd(&cnt[e], 1);
    tok[e * T_N + p] = t;
    wgt[e * T_N + p] = v;
  }
}

__global__ void k_prefix(const int* __restrict__ cnt, int* __restrict__ offs) {
  if (threadIdx.x == 0) {
    int s = 0;
    for (int e = 0; e < E_N; e++) { offs[e] = s; s += cnt[e]; }
  }
}

__global__ void k_cvt(const float* __restrict__ x, ushort* __restrict__ y) {
  int i = blockIdx.x * 256 + threadIdx.x;
  int base = i * 4;
  if (base >= T_N * H_N) return;
  float4v f = *(const float4v*)(x + base);
  short4v o;
  o.x = (short)f2bf(f.x); o.y = (short)f2bf(f.y);
  o.z = (short)f2bf(f.z); o.w = (short)f2bf(f.w);
  *(short4v*)(y + base) = o;
}

// ---------------- GEMM1: gu[r, n] = sum_h hid[tok[r], h] * gup[e, n, h] ----------------

__global__ __launch_bounds__(256, 2)
void k_gemm1(const ushort* __restrict__ hid,   // T x H bf16
             const float* __restrict__ gup,    // E x GU_N x H f32
             const int* __restrict__ cnt, const int* __restrict__ offs,
             const int* __restrict__ tok,
             ushort* __restrict__ gu) {        // compact rows x GU_N bf16
  int mtile = blockIdx.x, ntile = blockIdx.y, e = blockIdx.z;
  int ce = cnt[e];
  int row0 = mtile * BM;
  if (row0 >= ce) return;

  const float* B = gup + (size_t)e * GU_N * H_N;
  const int* tl = tok + e * T_N;
  int tid = threadIdx.x;

  __shared__ ushort As[BM * LSTR];
  __shared__ ushort Bs[BM * LSTR];

  int arow = tid >> 2;            // 0..63
  int acol = (tid & 3) << 3;      // bf16 col {0,8,16,24}
  int r0 = row0 + arow, r1 = row0 + 64 + arow;
  int t0 = tl[(r0 < ce) ? r0 : (ce - 1)];
  int t1 = tl[(r1 < ce) ? r1 : (ce - 1)];
  int brow = tid >> 3;            // 0..31
  int bcol = (tid & 7) << 2;      // f32 col
  int nbase = ntile * BN;

  int wid = tid >> 6, lane = tid & 63;
  int wm = (wid >> 1) & 1, wn = wid & 1;
  int l15 = lane & 15, quad = lane >> 4;

  float4v acc[4][4];
#pragma unroll
  for (int i = 0; i < 4; i++)
#pragma unroll
    for (int j = 0; j < 4; j++) acc[i][j] = (float4v){0.f, 0.f, 0.f, 0.f};

  for (int k0 = 0; k0 < H_N; k0 += BK) {
    __syncthreads();
    // Stage A (bf16, gathered rows): 2 issues x 64 rows
    {
      short8 v0 = *(const short8*)(hid + (size_t)t0 * H_N + k0 + acol);
      short8 v1 = *(const short8*)(hid + (size_t)t1 * H_N + k0 + acol);
      *(short8*)&As[arow * LSTR + acol] = v0;
      *(short8*)&As[(64 + arow) * LSTR + acol] = v1;
    }
    // Stage B (f32 -> bf16): 4 issues x 32 rows
#pragma unroll
    for (int s = 0; s < 4; s++) {
      int r = s * 32 + brow;
      float4v f = *(const float4v*)(B + (size_t)(nbase + r) * H_N + k0 + bcol);
      short4v o;
      o.x = (short)f2bf(f.x); o.y = (short)f2bf(f.y);
      o.z = (short)f2bf(f.z); o.w = (short)f2bf(f.w);
      *(short4v*)&Bs[r * LSTR + bcol] = o;
    }
    __syncthreads();

    short8 af[4], bfr[4];
#pragma unroll
    for (int i = 0; i < 4; i++)
      af[i] = *(const short8*)&As[(wm * 64 + i * 16 + l15) * LSTR + quad * 8];
#pragma unroll
    for (int j = 0; j < 4; j++)
      bfr[j] = *(const short8*)&Bs[(wn * 64 + j * 16 + l15) * LSTR + quad * 8];
#pragma unroll
    for (int i = 0; i < 4; i++)
#pragma unroll
      for (int j = 0; j < 4; j++)
        acc[i][j] = __builtin_amdgcn_mfma_f32_16x16x32_bf16(af[i], bfr[j], acc[i][j], 0, 0, 0);
  }

  int ob = offs[e];
#pragma unroll
  for (int i = 0; i < 4; i++)
#pragma unroll
    for (int j = 0; j < 4; j++)
#pragma unroll
      for (int r = 0; r < 4; r++) {
        int rr = row0 + wm * 64 + i * 16 + quad * 4 + r;
        if (rr < ce) {
          int cc = nbase + wn * 64 + j * 16 + l15;
          gu[(size_t)(ob + rr) * GU_N + cc] = f2bf(acc[i][j][r]);
        }
      }
}

// ---------------- activation: h = silu(gate) * up ----------------

__global__ void k_act(const ushort* __restrict__ gu, ushort* __restrict__ h,
                      const int* __restrict__ cnt, const int* __restrict__ offs) {
  int e = blockIdx.y, row = blockIdx.x;
  if (row >= cnt[e]) return;
  size_t gr = (size_t)offs[e] + row;
  const ushort* g = gu + gr * GU_N;
  ushort* hh = h + gr * I_N;
#pragma unroll
  for (int s = 0; s < 6; s++) {
    int c = s * 256 + threadIdx.x;
    float gate = bf2f(g[c]);
    float up = bf2f(g[I_N + c]);
    float sig = 1.f / (1.f + __expf(-gate));
    hh[c] = f2bf(gate * sig * up);
  }
}

// ---------------- GEMM2: out[tok[r], n] += w[r] * sum_i hact[r, i] * dwn[e, n, i] ----------------

__global__ __launch_bounds__(256, 2)
void k_gemm2(const ushort* __restrict__ hact,  // compact rows x I bf16
             const float* __restrict__ dwn,    // E x H x I f32
             const int* __restrict__ cnt, const int* __restrict__ offs,
             const int* __restrict__ tok, const float* __restrict__ wgt,
             float* __restrict__ out) {        // T x H f32
  int mtile = blockIdx.x, ntile = blockIdx.y, e = blockIdx.z;
  int ce = cnt[e];
  int row0 = mtile * BM;
  if (row0 >= ce) return;

  const float* B = dwn + (size_t)e * H_N * I_N;
  int ob = offs[e];
  int tid = threadIdx.x;

  __shared__ ushort As[BM * LSTR];
  __shared__ ushort Bs[BM * LSTR];

  int arow = tid >> 2;
  int acol = (tid & 3) << 3;
  int brow = tid >> 3;
  int bcol = (tid & 7) << 2;
  int nbase = ntile * BN;

  int wid = tid >> 6, lane = tid & 63;
  int wm = (wid >> 1) & 1, wn = wid & 1;
  int l15 = lane & 15, quad = lane >> 4;

  const ushort* Abase0 = hact + (size_t)(ob + row0 + arow) * I_N;
  const ushort* Abase1 = hact + (size_t)(ob + row0 + 64 + arow) * I_N;

  float4v acc[4][4];
#pragma unroll
  for (int i = 0; i < 4; i++)
#pragma unroll
    for (int j = 0; j < 4; j++) acc[i][j] = (float4v){0.f, 0.f, 0.f, 0.f};

  for (int k0 = 0; k0 < I_N; k0 += BK) {
    __syncthreads();
    {
      short8 v0 = *(const short8*)(Abase0 + k0 + acol);
      short8 v1 = *(const short8*)(Abase1 + k0 + acol);
      *(short8*)&As[arow * LSTR + acol] = v0;
      *(short8*)&As[(64 + arow) * LSTR + acol] = v1;
    }
#pragma unroll
    for (int s = 0; s < 4; s++) {
      int r = s * 32 + brow;
      float4v f = *(const float4v*)(B + (size_t)(nbase + r) * I_N + k0 + bcol);
      short4v o;
      o.x = (short)f2bf(f.x); o.y = (short)f2bf(f.y);
      o.z = (short)f2bf(f.z); o.w = (short)f2bf(f.w);
      *(short4v*)&Bs[r * LSTR + bcol] = o;
    }
    __syncthreads();

    short8 af[4], bfr[4];
#pragma unroll
    for (int i = 0; i < 4; i++)
      af[i] = *(const short8*)&As[(wm * 64 + i * 16 + l15) * LSTR + quad * 8];
#pragma unroll
    for (int j = 0; j < 4; j++)
      bfr[j] = *(const short8*)&Bs[(wn * 64 + j * 16 + l15) * LSTR + quad * 8];
#pragma unroll
    for (int i = 0; i < 4; i++)
#pragma unroll
      for (int j = 0; j < 4; j++)
        acc[i][j] = __builtin_amdgcn_mfma_f32_16x16x32_bf16(af[i], bfr[j], acc[i][j], 0, 0, 0);
  }

  const int* tl = tok + e * T_N;
  const float* wl = wgt + e * T_N;
#pragma unroll
  for (int i = 0; i < 4; i++)
#pragma unroll
    for (int j = 0; j < 4; j++)
#pragma unroll
      for (int r = 0; r < 4; r++) {
        int rr = row0 + wm * 64 + i * 16 + quad * 4 + r;
        if (rr < ce) {
          int t = tl[rr];
          float w = wl[rr];
          int cc = nbase + wn * 64 + j * 16 + l15;
          atomicAdd(&out[(size_t)t * H_N + cc], w * acc[i][j][r]);
        }
      }
}

// ---------------- launch ----------------

extern "C" void kernel_launch(void* const* d_in, const int* in_sizes, int n_in,
                              void* d_out, int out_size, void* d_ws, size_t ws_size,
                              hipStream_t stream) {
  (void)in_sizes; (void)n_in; (void)out_size; (void)ws_size;
  const float* hs  = (const float*)d_in[0];
  const int*   tki = (const int*)d_in[1];
  const float* tkw = (const float*)d_in[2];
  const float* gup = (const float*)d_in[3];
  const float* dwn = (const float*)d_in[4];
  float* out = (float*)d_out;

  char* ws = (char*)d_ws;
  size_t off = 0;
  auto alloc = [&](size_t bytes) {
    void* p = ws + off;
    off += (bytes + 255) & ~(size_t)255;
    return p;
  };
  float* w_full = (float*)alloc((size_t)T_N * E_N * 4);
  int*   cnt    = (int*)alloc(E_N * 4);
  int*   offs   = (int*)alloc(E_N * 4);
  int*   tok    = (int*)alloc((size_t)E_N * T_N * 4);
  float* wgt    = (float*)alloc((size_t)E_N * T_N * 4);
  ushort* hidb  = (ushort*)alloc((size_t)T_N * H_N * 2);
  const size_t CAP_ROWS = (size_t)T_N * K_N + 256;  // slack for tile over-read
  ushort* gu    = (ushort*)alloc(CAP_ROWS * GU_N * 2);
  ushort* hact  = (ushort*)alloc(CAP_ROWS * I_N * 2);

  k_init<<<(T_N * E_N + 255) / 256, 256, 0, stream>>>(w_full, cnt);
  k_scatter<<<(T_N * K_N + 255) / 256, 256, 0, stream>>>(tki, tkw, w_full);
  k_build<<<(T_N * E_N + 255) / 256, 256, 0, stream>>>(w_full, cnt, tok, wgt);
  k_prefix<<<1, 64, 0, stream>>>(cnt, offs);
  k_cvt<<<(T_N * H_N / 4 + 255) / 256, 256, 0, stream>>>(hs, hidb);

  dim3 g1(8, GU_N / BN, E_N);   // mtile fastest -> M-tiles sharing a B slab co-resident (L2 reuse)
  k_gemm1<<<g1, 256, 0, stream>>>(hidb, gup, cnt, offs, tok, gu);

  dim3 ga(T_N, E_N);
  k_act<<<ga, 256, 0, stream>>>(gu, hact, cnt, offs);

  (void)hipMemsetAsync(d_out, 0, (size_t)T_N * H_N * 4, stream);

  dim3 g2(8, H_N / BN, E_N);
  k_gemm2<<<g2, 256, 0, stream>>>(hact, dwn, cnt, offs, tok, wgt, out);
}